// Round 9
// baseline (47.743 us; speedup 1.0000x reference)
//
#include <hip/hip_runtime.h>

#define NQ 12
#define DIM 4096
#define BLK 256
#define REPS 4   // DIAGNOSTIC: repeat the full circuit in-kernel to expose
                 // counters (amortizes launch overhead; output unchanged).

typedef float v2f __attribute__((ext_vector_type(2)));

// gray-to-binary (== CNOT chain relabel): bit i of result = XOR of bits >= i.
__host__ __device__ constexpr int igrayc(int v) {
    v ^= v >> 1; v ^= v >> 2; v ^= v >> 4; v ^= v >> 8;
    return v & (DIM - 1);
}
// binary-to-gray composed k times: g^1=v^(v>>1), g^2=v^(v>>2), g^3=g^1∘g^2
__host__ __device__ constexpr int gkf(int v, int k) {
    if (k == 1) v ^= v >> 1;
    else if (k == 2) v ^= v >> 2;
    else { v ^= v >> 2; v ^= v >> 1; }
    return v;
}
// LDS swizzle (involution) — bank-pair = low4(sig); rank-4 verified per pass.
__host__ __device__ constexpr int sigf(int v) { return v ^ ((v >> 4) & 15); }
// slot of logical label n at epoch k (k CNOT layers folded): slot = sig(m)
__host__ __device__ constexpr int TkF(int v, int k) { return sigf(gkf(v, k)); }

__device__ __forceinline__ v2f cmul(v2f a, v2f b) {
    v2f r; r.x = a.x * b.x - a.y * b.y; r.y = a.x * b.y + a.y * b.x; return r;
}
__device__ __forceinline__ void gate_pair(v2f& a0, v2f& a1, float c, float s) {
    v2f t0 = a0, t1 = a1;
    a0 = c * t0 - s * t1;
    a1 = s * t0 + c * t1;
}
template<int PB>
__device__ __forceinline__ void gate16(v2f (&a)[16], float c, float s) {
    #pragma unroll
    for (int j0 = 0; j0 < 16; ++j0) {
        if (j0 & PB) continue;
        gate_pair(a[j0], a[j0 | PB], c, s);
    }
}
template<int K, int OSH>
__device__ __forceinline__ void ld16(const char* bufc, int sb8, v2f (&a)[16]) {
    #pragma unroll
    for (int j = 0; j < 16; ++j)
        a[j] = *(const v2f*)(bufc + (sb8 ^ (TkF(j << OSH, K) << 3)));
}
template<int K, int OSH>
__device__ __forceinline__ void st16(char* bufc, int sb8, const v2f (&a)[16]) {
    #pragma unroll
    for (int j = 0; j < 16; ++j)
        *(v2f*)(bufc + (sb8 ^ (TkF(j << OSH, K) << 3))) = a[j];
}

// wave64 sum on the VALU pipe (DPP row ops), result valid in lane 63
__device__ __forceinline__ float wave64_sum(float v) {
    v += __int_as_float(__builtin_amdgcn_update_dpp(0, __float_as_int(v), 0x111, 0xf, 0xf, true));
    v += __int_as_float(__builtin_amdgcn_update_dpp(0, __float_as_int(v), 0x112, 0xf, 0xf, true));
    v += __int_as_float(__builtin_amdgcn_update_dpp(0, __float_as_int(v), 0x114, 0xf, 0xf, true));
    v += __int_as_float(__builtin_amdgcn_update_dpp(0, __float_as_int(v), 0x118, 0xf, 0xf, true));
    v += __int_as_float(__builtin_amdgcn_update_dpp(0, __float_as_int(v), 0x142, 0xa, 0xf, false));
    v += __int_as_float(__builtin_amdgcn_update_dpp(0, __float_as_int(v), 0x143, 0xc, 0xf, false));
    return v;
}

__global__ __launch_bounds__(BLK, 2)
void qsim_kernel(const float* __restrict__ x,
                 const float* __restrict__ rys,
                 float* __restrict__ out) {
    __shared__ __align__(16) v2f buf[DIM];           // 32 KB, slot = sig(m) forever
    __shared__ float cr[4 * NQ], sr[4 * NQ];
    __shared__ v2f fac[NQ][2];                       // init factors (d0 RY absorbed)
    __shared__ float zred[4][NQ];

    const int b = blockIdx.x;
    const int t = threadIdx.x;                       // 8 bits
    char* bufc = (char*)buf;

    if (t < 4 * NQ) {
        float th = 0.5f * rys[t];
        cr[t] = cosf(th); sr[t] = sinf(th);
    }
    if (t >= 64 && t < 64 + NQ) {
        int q = t - 64;
        float xh = 0.5f * x[b * NQ + q];
        float cx = cosf(xh), sx = sinf(xh);
        float th = 0.5f * rys[q];                    // layer-0 RY absorbed
        float c0 = cosf(th), s0 = sinf(th);
        int p = NQ - 1 - q;                          // bit position of qubit q
        fac[p][0] = v2f{c0 * cx,  s0 * sx};          // (RY·RX)|0>, bit=0
        fac[p][1] = v2f{s0 * cx, -c0 * sx};          // bit=1
    }
    __syncthreads();

    // base embeddings (logical-label base per pass family)
    const int nbB = (t & 15) | (((t >> 4) & 15) << 8);             // B: bits{0-3,8-11}
    const int nbA7 = ((t & 3) << 4) | (((t >> 2) & 15) << 8)
                   | (((t >> 6) & 3) << 6);                        // P7 lane fix

    #pragma unroll 1
    for (int rep = 0; rep < REPS; ++rep) {
    // ---- P0: build product state (n1 coords), pregate L1 q3-0, store ----
    {
        v2f a[16];
        const int Mb = t ^ (t >> 1);                 // m bits 0..7 (bit7 = t7)
        v2f P = fac[0][Mb & 1];
        #pragma unroll
        for (int p = 1; p < 7; ++p) P = cmul(P, fac[p][(Mb >> p) & 1]);
        const int b7 = (Mb >> 7) & 1;
        v2f E = cmul(P, fac[7][b7]);                 // register j even
        v2f O = cmul(P, fac[7][b7 ^ 1]);             // register j odd
        v2f L4[4], H4[4];
        #pragma unroll
        for (int v = 0; v < 4; ++v) {
            L4[v] = cmul(fac[8][v & 1],  fac[9][(v >> 1) & 1]);
            H4[v] = cmul(fac[10][v & 1], fac[11][(v >> 1) & 1]);
        }
        #pragma unroll
        for (int j = 0; j < 16; ++j) {
            const int gv = (j ^ (j >> 1)) & 15;      // m bits 8-11 of this register
            a[j] = cmul((j & 1) ? O : E, cmul(L4[gv & 3], H4[(gv >> 2) & 3]));
        }
        gate16<1>(a, cr[15], sr[15]);                // L1 q3 (n1 bit 8)
        gate16<2>(a, cr[14], sr[14]);                // q2
        gate16<4>(a, cr[13], sr[13]);                // q1
        gate16<8>(a, cr[12], sr[12]);                // q0
        st16<1, 8>(bufc, TkF(t, 1) << 3, a);
    }
    __syncthreads();

    #define GATE_PASS(K, NB, OSH, I0, I1, I2, I3)                 \
    {                                                             \
        const int sb8 = TkF(NB, K) << 3;                          \
        v2f a[16];                                                \
        ld16<K, OSH>(bufc, sb8, a);                               \
        gate16<1>(a, cr[I0], sr[I0]);                             \
        gate16<2>(a, cr[I1], sr[I1]);                             \
        gate16<4>(a, cr[I2], sr[I2]);                             \
        gate16<8>(a, cr[I3], sr[I3]);                             \
        st16<K, OSH>(bufc, sb8, a);                               \
    }                                                             \
    __syncthreads();

    GATE_PASS(1, (t << 4), 0, 23, 22, 21, 20)   // P1: L1 q11-8
    GATE_PASS(1, nbB,      4, 19, 18, 17, 16)   // P2: L1 q7-4
    GATE_PASS(2, t,        8, 27, 26, 25, 24)   // P3: relabel2 + L2 q3-0
    GATE_PASS(2, (t << 4), 0, 35, 34, 33, 32)   // P4: L2 q11-8
    GATE_PASS(2, nbB,      4, 31, 30, 29, 28)   // P5: L2 q7-4
    GATE_PASS(3, t,        8, 39, 38, 37, 36)   // P6: relabel3 + L3 q3-0
    GATE_PASS(3, nbA7,     0, 47, 46, 45, 44)   // P7: L3 q11-8
    #undef GATE_PASS

    // ---- P8: L3 q7-4 + relabel4 (labels only) + Z, no store ----
    {
        const int sb8 = TkF(nbB, 3) << 3;
        v2f a[16];
        ld16<3, 4>(bufc, sb8, a);
        gate16<1>(a, cr[43], sr[43]);
        gate16<2>(a, cr[42], sr[42]);
        gate16<4>(a, cr[41], sr[41]);
        gate16<8>(a, cr[40], sr[40]);

        float zacc[NQ];
        #pragma unroll
        for (int q = 0; q < NQ; ++q) zacc[q] = 0.0f;
        #pragma unroll
        for (int j = 0; j < 16; ++j) {
            const int nc = igrayc(j << 4);           // compile-time n4 offset
            const float pr = a[j].x * a[j].x + a[j].y * a[j].y;
            #pragma unroll
            for (int q = 0; q < NQ; ++q)
                zacc[q] += ((nc >> (NQ - 1 - q)) & 1) ? -pr : pr;
        }
        const int R = igrayc(nbB);                   // runtime n4 base
        #pragma unroll
        for (int q = 0; q < NQ; ++q) {
            float v = ((R >> (NQ - 1 - q)) & 1) ? -zacc[q] : zacc[q];
            v = wave64_sum(v);
            if ((t & 63) == 63) zred[t >> 6][q] = v;
        }
    }
    __syncthreads();   // also orders P8 reads before next rep's P0 stores
    }   // rep

    if (t < NQ)
        out[b * NQ + t] = zred[0][t] + zred[1][t] + zred[2][t] + zred[3][t];
}

extern "C" void kernel_launch(void* const* d_in, const int* in_sizes, int n_in,
                              void* d_out, int out_size, void* d_ws, size_t ws_size,
                              hipStream_t stream) {
    const float* x   = (const float*)d_in[0];
    const float* rys = (const float*)d_in[1];
    // d_in[2] (cnot_params) unused by the reference — CNOT takes no params.
    float* out = (float*)d_out;
    qsim_kernel<<<512, BLK, 0, stream>>>(x, rys, out);
}

// Round 10
// 17.200 us; speedup vs baseline: 2.7757x; 2.7757x over previous
//
#include <hip/hip_runtime.h>

#define NQ 12
#define DIM 4096
#define BLK 256

typedef float v2f __attribute__((ext_vector_type(2)));

// gray-to-binary (== CNOT chain relabel): bit i of result = XOR of bits >= i.
__host__ __device__ constexpr int igrayc(int v) {
    v ^= v >> 1; v ^= v >> 2; v ^= v >> 4; v ^= v >> 8;
    return v & (DIM - 1);
}
// binary-to-gray composed k times: g^1=v^(v>>1), g^2=v^(v>>2), g^3=g^1∘g^2
__host__ __device__ constexpr int gkf(int v, int k) {
    if (k == 1) v ^= v >> 1;
    else if (k == 2) v ^= v >> 2;
    else { v ^= v >> 2; v ^= v >> 1; }
    return v;
}
// LDS swizzle (involution); bank-pair = low4(slot).
__host__ __device__ constexpr int sigf(int v) { return v ^ ((v >> 4) & 15); }
// slot of logical label n at epoch k (k CNOT layers folded): slot = sig(m)
__host__ __device__ constexpr int TkF(int v, int k) { return sigf(gkf(v, k)); }

__device__ __forceinline__ v2f cmul(v2f a, v2f b) {
    v2f r; r.x = a.x * b.x - a.y * b.y; r.y = a.x * b.y + a.y * b.x; return r;
}
// RY pair, packed f32 math: 2x v_pk_mul + 2x v_pk_fma
__device__ __forceinline__ void gate_pair(v2f& a0, v2f& a1, v2f cc, v2f ss, v2f ns) {
    v2f t0 = a0, t1 = a1;
    a0 = __builtin_elementwise_fma(ns, t1, cc * t0);   // c*a0 - s*a1
    a1 = __builtin_elementwise_fma(ss, t0, cc * t1);   // s*a0 + c*a1
}
template<int PB>
__device__ __forceinline__ void gate16(v2f (&a)[16], float c, float s) {
    const v2f cc = {c, c}, ss = {s, s}, ns = {-s, -s};
    #pragma unroll
    for (int j0 = 0; j0 < 16; ++j0) {
        if (j0 & PB) continue;
        gate_pair(a[j0], a[j0 | PB], cc, ss, ns);
    }
}
template<int K, int OSH>
__device__ __forceinline__ void ld16(const char* bufc, int sb8, v2f (&a)[16]) {
    #pragma unroll
    for (int j = 0; j < 16; ++j)
        a[j] = *(const v2f*)(bufc + (sb8 ^ (TkF(j << OSH, K) << 3)));
}
template<int K, int OSH>
__device__ __forceinline__ void st16(char* bufc, int sb8, const v2f (&a)[16]) {
    #pragma unroll
    for (int j = 0; j < 16; ++j)
        *(v2f*)(bufc + (sb8 ^ (TkF(j << OSH, K) << 3))) = a[j];
}

// wave64 sum on the VALU pipe (DPP row ops), result valid in lane 63
__device__ __forceinline__ float wave64_sum(float v) {
    v += __int_as_float(__builtin_amdgcn_update_dpp(0, __float_as_int(v), 0x111, 0xf, 0xf, true));
    v += __int_as_float(__builtin_amdgcn_update_dpp(0, __float_as_int(v), 0x112, 0xf, 0xf, true));
    v += __int_as_float(__builtin_amdgcn_update_dpp(0, __float_as_int(v), 0x114, 0xf, 0xf, true));
    v += __int_as_float(__builtin_amdgcn_update_dpp(0, __float_as_int(v), 0x118, 0xf, 0xf, true));
    v += __int_as_float(__builtin_amdgcn_update_dpp(0, __float_as_int(v), 0x142, 0xa, 0xf, false));
    v += __int_as_float(__builtin_amdgcn_update_dpp(0, __float_as_int(v), 0x143, 0xc, 0xf, false));
    return v;
}

__global__ __launch_bounds__(BLK, 2)
void qsim_kernel(const float* __restrict__ x,
                 const float* __restrict__ rys,
                 float* __restrict__ out) {
    __shared__ __align__(16) v2f buf[DIM];           // 32 KB, slot = sig(m) forever
    __shared__ float cr[4 * NQ], sr[4 * NQ];
    __shared__ v2f fac[NQ][2];                       // init factors (d0 RY absorbed)
    __shared__ float zred[4][NQ];

    const int b = blockIdx.x;
    const int t = threadIdx.x;                       // 8 bits
    char* bufc = (char*)buf;

    if (t < 4 * NQ) {
        float th = 0.5f * rys[t];
        cr[t] = cosf(th); sr[t] = sinf(th);
    }
    if (t >= 64 && t < 64 + NQ) {
        int q = t - 64;
        float xh = 0.5f * x[b * NQ + q];
        float cx = cosf(xh), sx = sinf(xh);
        float th = 0.5f * rys[q];                    // layer-0 RY absorbed
        float c0 = cosf(th), s0 = sinf(th);
        int p = NQ - 1 - q;                          // bit position of qubit q
        fac[p][0] = v2f{c0 * cx,  s0 * sx};          // (RY·RX)|0>, bit=0
        fac[p][1] = v2f{s0 * cx, -c0 * sx};          // bit=1
    }
    __syncthreads();

    // base embeddings (logical-label base per pass family). Lane->label-bit
    // assignments chosen so every pass's 16-lane issue-group maps rank-4 onto
    // bank-pairs (conflict-free b64), incl. the K=2 (P4) and K=3 (P7) A-passes.
    const int nbB  = (t & 15) | (((t >> 4) & 15) << 8);            // bits{0-3,8-11}
    const int nbA4 = ((t & 3) << 4) | (((t >> 2) & 3) << 8)        // P4: t->n{4,5,8,9,
                   | (((t >> 4) & 3) << 6) | (((t >> 6) & 3) << 10);//       6,7,10,11}
    const int nbA7 = ((t & 1) << 4) | (((t >> 1) & 7) << 8)        // P7: t->n{4,8,9,10,
                   | (((t >> 4) & 3) << 5) | (((t >> 6) & 1) << 7) //       5,6,7,11}
                   | (((t >> 7) & 1) << 11);

    // ---- P0: build product state (n1 coords), pregate L1 q3-0, store ----
    {
        v2f a[16];
        const int Mb = t ^ (t >> 1);                 // m bits 0..7 (bit7 = t7)
        v2f P = fac[0][Mb & 1];
        #pragma unroll
        for (int p = 1; p < 7; ++p) P = cmul(P, fac[p][(Mb >> p) & 1]);
        const int b7 = (Mb >> 7) & 1;
        v2f E = cmul(P, fac[7][b7]);                 // register j even
        v2f O = cmul(P, fac[7][b7 ^ 1]);             // register j odd
        v2f L4[4], H4[4];
        #pragma unroll
        for (int v = 0; v < 4; ++v) {
            L4[v] = cmul(fac[8][v & 1],  fac[9][(v >> 1) & 1]);
            H4[v] = cmul(fac[10][v & 1], fac[11][(v >> 1) & 1]);
        }
        #pragma unroll
        for (int j = 0; j < 16; ++j) {
            const int gv = (j ^ (j >> 1)) & 15;      // m bits 8-11 of this register
            a[j] = cmul((j & 1) ? O : E, cmul(L4[gv & 3], H4[(gv >> 2) & 3]));
        }
        gate16<1>(a, cr[15], sr[15]);                // L1 q3 (n1 bit 8)
        gate16<2>(a, cr[14], sr[14]);                // q2
        gate16<4>(a, cr[13], sr[13]);                // q1
        gate16<8>(a, cr[12], sr[12]);                // q0
        st16<1, 8>(bufc, TkF(t, 1) << 3, a);
    }
    __syncthreads();

    #define GATE_PASS(K, NB, OSH, I0, I1, I2, I3)                 \
    {                                                             \
        const int sb8 = TkF(NB, K) << 3;                          \
        v2f a[16];                                                \
        ld16<K, OSH>(bufc, sb8, a);                               \
        gate16<1>(a, cr[I0], sr[I0]);                             \
        gate16<2>(a, cr[I1], sr[I1]);                             \
        gate16<4>(a, cr[I2], sr[I2]);                             \
        gate16<8>(a, cr[I3], sr[I3]);                             \
        st16<K, OSH>(bufc, sb8, a);                               \
    }                                                             \
    __syncthreads();

    GATE_PASS(1, (t << 4), 0, 23, 22, 21, 20)   // P1: L1 q11-8
    GATE_PASS(1, nbB,      4, 19, 18, 17, 16)   // P2: L1 q7-4
    GATE_PASS(2, t,        8, 27, 26, 25, 24)   // P3: relabel2 + L2 q3-0
    GATE_PASS(2, nbA4,     0, 35, 34, 33, 32)   // P4: L2 q11-8 (rank-4 embed)
    GATE_PASS(2, nbB,      4, 31, 30, 29, 28)   // P5: L2 q7-4
    GATE_PASS(3, t,        8, 39, 38, 37, 36)   // P6: relabel3 + L3 q3-0
    GATE_PASS(3, nbA7,     0, 47, 46, 45, 44)   // P7: L3 q11-8 (rank-4 embed)
    #undef GATE_PASS

    // ---- P8: L3 q7-4 + relabel4 (labels only) + Z via 16-pt WHT, no store ----
    {
        const int sb8 = TkF(nbB, 3) << 3;
        v2f a[16];
        ld16<3, 4>(bufc, sb8, a);
        gate16<1>(a, cr[43], sr[43]);
        gate16<2>(a, cr[42], sr[42]);
        gate16<4>(a, cr[41], sr[41]);
        gate16<8>(a, cr[40], sr[40]);

        float pr[16];
        #pragma unroll
        for (int j = 0; j < 16; ++j)
            pr[j] = a[j].x * a[j].x + a[j].y * a[j].y;
        // Walsh-Hadamard over the 4 register bits: pr[v] = sum_j (-1)^{popc(j&v)} pr0[j]
        #pragma unroll
        for (int bit = 1; bit < 16; bit <<= 1) {
            #pragma unroll
            for (int j = 0; j < 16; ++j) {
                if (j & bit) continue;
                float u = pr[j], w = pr[j | bit];
                pr[j] = u + w;
                pr[j | bit] = u - w;
            }
        }
        // register j flips label bits igray(e_{4+b}) = (2^{5+b}-1):
        // label bit l needs WH at v: l<=4 -> 15; l=5 -> 14; l=6 -> 12; l=7 -> 8; l>=8 -> 0
        const int R = igrayc(nbB);                   // runtime label base (n4)
        #pragma unroll
        for (int q = 0; q < NQ; ++q) {
            const int l = NQ - 1 - q;
            const float cf = (l <= 4) ? pr[15]
                           : (l == 5) ? pr[14]
                           : (l == 6) ? pr[12]
                           : (l == 7) ? pr[8]  : pr[0];
            float v = ((R >> l) & 1) ? -cf : cf;
            v = wave64_sum(v);
            if ((t & 63) == 63) zred[t >> 6][q] = v;
        }
    }
    __syncthreads();
    if (t < NQ)
        out[b * NQ + t] = zred[0][t] + zred[1][t] + zred[2][t] + zred[3][t];
}

extern "C" void kernel_launch(void* const* d_in, const int* in_sizes, int n_in,
                              void* d_out, int out_size, void* d_ws, size_t ws_size,
                              hipStream_t stream) {
    const float* x   = (const float*)d_in[0];
    const float* rys = (const float*)d_in[1];
    // d_in[2] (cnot_params) unused by the reference — CNOT takes no params.
    float* out = (float*)d_out;
    qsim_kernel<<<512, BLK, 0, stream>>>(x, rys, out);
}

// Round 11
// 16.737 us; speedup vs baseline: 2.8525x; 1.0277x over previous
//
#include <hip/hip_runtime.h>

#define NQ 12
#define DIM 4096
#define BLK 256

typedef float v2f __attribute__((ext_vector_type(2)));

// gray-to-binary (== CNOT chain relabel): bit i of result = XOR of bits >= i.
__host__ __device__ constexpr int igrayc(int v) {
    v ^= v >> 1; v ^= v >> 2; v ^= v >> 4; v ^= v >> 8;
    return v & (DIM - 1);
}
// binary-to-gray composed k times: g^1=v^(v>>1), g^2=v^(v>>2), g^3=g^1∘g^2
__host__ __device__ constexpr int gkf(int v, int k) {
    if (k == 1) v ^= v >> 1;
    else if (k == 2) v ^= v >> 2;
    else { v ^= v >> 2; v ^= v >> 1; }
    return v;
}
// LDS swizzle (involution); bank-pair = low4(slot).
__host__ __device__ constexpr int sigf(int v) { return v ^ ((v >> 4) & 15); }
// slot of logical label n at epoch k (k CNOT layers folded): slot = sig(m)
__host__ __device__ constexpr int TkF(int v, int k) { return sigf(gkf(v, k)); }

__device__ __forceinline__ v2f cmul(v2f a, v2f b) {
    v2f r; r.x = a.x * b.x - a.y * b.y; r.y = a.x * b.y + a.y * b.x; return r;
}
// RY pair, packed f32 math
__device__ __forceinline__ void gate_pair(v2f& a0, v2f& a1, v2f cc, v2f ss, v2f ns) {
    v2f t0 = a0, t1 = a1;
    a0 = __builtin_elementwise_fma(ns, t1, cc * t0);   // c*a0 - s*a1
    a1 = __builtin_elementwise_fma(ss, t0, cc * t1);   // s*a0 + c*a1
}
template<int PB>
__device__ __forceinline__ void gate16(v2f (&a)[16], float c, float s) {
    const v2f cc = {c, c}, ss = {s, s}, ns = {-s, -s};
    #pragma unroll
    for (int j0 = 0; j0 < 16; ++j0) {
        if (j0 & PB) continue;
        gate_pair(a[j0], a[j0 | PB], cc, ss, ns);
    }
}

// RY gate whose pairing is ACROSS LANES via DPP (VALU pipe, no LDS traffic).
// Partner lane = l ^ M (CTRL implements the XOR); BETA = label bit hosted.
// Both sides: a' = c*a + sl*b where sl = +s if our label bit is 1, else -s.
template<int CTRL, int BETA>
__device__ __forceinline__ void dpp_gate16(v2f (&a)[16], float c, float s, int lb) {
    const float sl = ((lb >> BETA) & 1) ? s : -s;
    const v2f cc = {c, c}, sv = {sl, sl};
    #pragma unroll
    for (int j = 0; j < 16; ++j) {
        int bx = __builtin_amdgcn_update_dpp(0, __float_as_int(a[j].x), CTRL, 0xf, 0xf, true);
        int by = __builtin_amdgcn_update_dpp(0, __float_as_int(a[j].y), CTRL, 0xf, 0xf, true);
        v2f b; b.x = __int_as_float(bx); b.y = __int_as_float(by);
        a[j] = __builtin_elementwise_fma(sv, b, cc * a[j]);
    }
}
#define DPP_XOR1  0xB1   // quad_perm [1,0,3,2]
#define DPP_XOR2  0x4E   // quad_perm [2,3,0,1]
#define DPP_XOR7  0x141  // row_half_mirror
#define DPP_XOR15 0x140  // row_mirror

template<int K, int OSH>
__device__ __forceinline__ void ld16(const char* bufc, int sb8, v2f (&a)[16]) {
    #pragma unroll
    for (int j = 0; j < 16; ++j)
        a[j] = *(const v2f*)(bufc + (sb8 ^ (TkF(j << OSH, K) << 3)));
}
template<int K, int OSH>
__device__ __forceinline__ void st16(char* bufc, int sb8, const v2f (&a)[16]) {
    #pragma unroll
    for (int j = 0; j < 16; ++j)
        *(v2f*)(bufc + (sb8 ^ (TkF(j << OSH, K) << 3))) = a[j];
}

// wave64 sum on the VALU pipe (DPP row ops), result valid in lane 63
__device__ __forceinline__ float wave64_sum(float v) {
    v += __int_as_float(__builtin_amdgcn_update_dpp(0, __float_as_int(v), 0x111, 0xf, 0xf, true));
    v += __int_as_float(__builtin_amdgcn_update_dpp(0, __float_as_int(v), 0x112, 0xf, 0xf, true));
    v += __int_as_float(__builtin_amdgcn_update_dpp(0, __float_as_int(v), 0x114, 0xf, 0xf, true));
    v += __int_as_float(__builtin_amdgcn_update_dpp(0, __float_as_int(v), 0x118, 0xf, 0xf, true));
    v += __int_as_float(__builtin_amdgcn_update_dpp(0, __float_as_int(v), 0x142, 0xa, 0xf, false));
    v += __int_as_float(__builtin_amdgcn_update_dpp(0, __float_as_int(v), 0x143, 0xc, 0xf, false));
    return v;
}

__global__ __launch_bounds__(BLK, 2)
void qsim_kernel(const float* __restrict__ x,
                 const float* __restrict__ rys,
                 float* __restrict__ out) {
    __shared__ __align__(16) v2f buf[DIM];           // 32 KB, slot = sig(m) forever
    __shared__ float cr[4 * NQ], sr[4 * NQ];
    __shared__ v2f fac[NQ][2];                       // init factors (d0 RY absorbed)
    __shared__ float zred[4][NQ];

    const int b = blockIdx.x;
    const int t = threadIdx.x;                       // 8 bits
    char* bufc = (char*)buf;

    if (t < 4 * NQ) {
        float th = 0.5f * rys[t];
        cr[t] = cosf(th); sr[t] = sinf(th);
    }
    if (t >= 64 && t < 64 + NQ) {
        int q = t - 64;
        float xh = 0.5f * x[b * NQ + q];
        float cx = cosf(xh), sx = sinf(xh);
        float th = 0.5f * rys[q];                    // layer-0 RY absorbed
        float c0 = cosf(th), s0 = sinf(th);
        int p = NQ - 1 - q;                          // bit position of qubit q
        fac[p][0] = v2f{c0 * cx,  s0 * sx};          // (RY·RX)|0>, bit=0
        fac[p][1] = v2f{s0 * cx, -c0 * sx};          // bit=1
    }
    __syncthreads();

    // AB-pass lane base: E maps DPP masks {1,2,7,15}->label bits e0..e3,
    // lanes t4,t5 -> e8,e9, wave bits t6,t7 -> e10,e11. (rank-4 bank spread
    // verified per 16-lane group for K=1,2,3: {1,3,6,12},{1,2,5,10},{1,3,7,15})
    const int lb = (t & 3) ^ (((t >> 2) & 1) * 7) ^ (((t >> 3) & 1) * 12)
                 ^ ((t >> 4) << 8);

    // ---- P0: build product state (n1 coords), pregate L1 q3-0, store ----
    {
        v2f a[16];
        const int Mb = t ^ (t >> 1);                 // m bits 0..7 (bit7 = t7)
        v2f P = fac[0][Mb & 1];
        #pragma unroll
        for (int p = 1; p < 7; ++p) P = cmul(P, fac[p][(Mb >> p) & 1]);
        const int b7 = (Mb >> 7) & 1;
        v2f E = cmul(P, fac[7][b7]);                 // register j even
        v2f O = cmul(P, fac[7][b7 ^ 1]);             // register j odd
        v2f L4[4], H4[4];
        #pragma unroll
        for (int v = 0; v < 4; ++v) {
            L4[v] = cmul(fac[8][v & 1],  fac[9][(v >> 1) & 1]);
            H4[v] = cmul(fac[10][v & 1], fac[11][(v >> 1) & 1]);
        }
        #pragma unroll
        for (int j = 0; j < 16; ++j) {
            const int gv = (j ^ (j >> 1)) & 15;      // m bits 8-11 of this register
            a[j] = cmul((j & 1) ? O : E, cmul(L4[gv & 3], H4[(gv >> 2) & 3]));
        }
        gate16<1>(a, cr[15], sr[15]);                // L1 q3 (n1 bit 8)
        gate16<2>(a, cr[14], sr[14]);                // q2
        gate16<4>(a, cr[13], sr[13]);                // q1
        gate16<8>(a, cr[12], sr[12]);                // q0
        st16<1, 8>(bufc, TkF(t, 1) << 3, a);
    }
    __syncthreads();

    // One AB-pass per layer: 4 reg gates (bits 4-7 = q7-4) + 4 DPP gates
    // (bits 0-3 = q11-8). In-place, same epoch K.
    #define AB_PASS(K, D)                                          \
    {                                                              \
        const int sb8 = TkF(lb, K) << 3;                           \
        v2f a[16];                                                 \
        ld16<K, 4>(bufc, sb8, a);                                  \
        gate16<1>(a, cr[(D)*NQ + 7], sr[(D)*NQ + 7]);              \
        gate16<2>(a, cr[(D)*NQ + 6], sr[(D)*NQ + 6]);              \
        gate16<4>(a, cr[(D)*NQ + 5], sr[(D)*NQ + 5]);              \
        gate16<8>(a, cr[(D)*NQ + 4], sr[(D)*NQ + 4]);              \
        dpp_gate16<DPP_XOR1,  0>(a, cr[(D)*NQ + 11], sr[(D)*NQ + 11], lb); \
        dpp_gate16<DPP_XOR2,  1>(a, cr[(D)*NQ + 10], sr[(D)*NQ + 10], lb); \
        dpp_gate16<DPP_XOR7,  2>(a, cr[(D)*NQ + 9],  sr[(D)*NQ + 9],  lb); \
        dpp_gate16<DPP_XOR15, 3>(a, cr[(D)*NQ + 8],  sr[(D)*NQ + 8],  lb); \
        st16<K, 4>(bufc, sb8, a);                                  \
    }                                                              \
    __syncthreads();

    // C-pass: relabel (K bump at load) + next layer's q3-0 on register bits 8-11
    #define C_PASS(K, I0, I1, I2, I3)                              \
    {                                                              \
        const int sb8 = TkF(t, K) << 3;                            \
        v2f a[16];                                                 \
        ld16<K, 8>(bufc, sb8, a);                                  \
        gate16<1>(a, cr[I0], sr[I0]);                              \
        gate16<2>(a, cr[I1], sr[I1]);                              \
        gate16<4>(a, cr[I2], sr[I2]);                              \
        gate16<8>(a, cr[I3], sr[I3]);                              \
        st16<K, 8>(bufc, sb8, a);                                  \
    }                                                              \
    __syncthreads();

    AB_PASS(1, 1)                      // P1: L1 q11-4
    C_PASS(2, 27, 26, 25, 24)          // P2: relabel2 + L2 q3-0
    AB_PASS(2, 2)                      // P3: L2 q11-4
    C_PASS(3, 39, 38, 37, 36)          // P4: relabel3 + L3 q3-0
    #undef AB_PASS
    #undef C_PASS

    // ---- P5: L3 q11-4 + relabel4 (labels only) + Z via 16-pt WHT, no store ----
    {
        const int sb8 = TkF(lb, 3) << 3;
        v2f a[16];
        ld16<3, 4>(bufc, sb8, a);
        gate16<1>(a, cr[43], sr[43]);
        gate16<2>(a, cr[42], sr[42]);
        gate16<4>(a, cr[41], sr[41]);
        gate16<8>(a, cr[40], sr[40]);
        dpp_gate16<DPP_XOR1,  0>(a, cr[47], sr[47], lb);
        dpp_gate16<DPP_XOR2,  1>(a, cr[46], sr[46], lb);
        dpp_gate16<DPP_XOR7,  2>(a, cr[45], sr[45], lb);
        dpp_gate16<DPP_XOR15, 3>(a, cr[44], sr[44], lb);

        float pr[16];
        #pragma unroll
        for (int j = 0; j < 16; ++j)
            pr[j] = a[j].x * a[j].x + a[j].y * a[j].y;
        // WHT over register bits (label dirs e4..e7)
        #pragma unroll
        for (int bit = 1; bit < 16; bit <<= 1) {
            #pragma unroll
            for (int j = 0; j < 16; ++j) {
                if (j & bit) continue;
                float u = pr[j], w = pr[j | bit];
                pr[j] = u + w;
                pr[j | bit] = u - w;
            }
        }
        // register dir e_{4+i}: igray sets bits 0..4+i -> label bit l needs WH at
        // v_i = [l <= 4+i]: l<=4 -> 15; l=5 -> 14; l=6 -> 12; l=7 -> 8; l>=8 -> 0
        const int R = igrayc(lb);                    // runtime label base (n4)
        #pragma unroll
        for (int q = 0; q < NQ; ++q) {
            const int l = NQ - 1 - q;
            const float cf = (l <= 4) ? pr[15]
                           : (l == 5) ? pr[14]
                           : (l == 6) ? pr[12]
                           : (l == 7) ? pr[8]  : pr[0];
            float v = ((R >> l) & 1) ? -cf : cf;
            v = wave64_sum(v);
            if ((t & 63) == 63) zred[t >> 6][q] = v;
        }
    }
    __syncthreads();
    if (t < NQ)
        out[b * NQ + t] = zred[0][t] + zred[1][t] + zred[2][t] + zred[3][t];
}

extern "C" void kernel_launch(void* const* d_in, const int* in_sizes, int n_in,
                              void* d_out, int out_size, void* d_ws, size_t ws_size,
                              hipStream_t stream) {
    const float* x   = (const float*)d_in[0];
    const float* rys = (const float*)d_in[1];
    // d_in[2] (cnot_params) unused by the reference — CNOT takes no params.
    float* out = (float*)d_out;
    qsim_kernel<<<512, BLK, 0, stream>>>(x, rys, out);
}